// Round 1
// baseline (477.868 us; speedup 1.0000x reference)
//
#include <hip/hip_runtime.h>
#include <stdint.h>
#include <stddef.h>

#define HIDDEN 2048
#define INTER  5632
#define TOKENS 4096   // B*S = 2*2048
#define BK     64     // K-tile for both GEMMs (i8: 64B rows, f16: 128B rows)
#define NT_GU  (HIDDEN / BK)   // 32
#define NT_DN  (INTER / BK)    // 88

typedef __attribute__((ext_vector_type(8))) _Float16 f16x8;
typedef __attribute__((ext_vector_type(4))) _Float16 f16x4;
typedef __attribute__((ext_vector_type(4))) float    f32x4;
typedef __attribute__((ext_vector_type(4))) int      i32x4;

// 128B-row LDS swizzle (8 x 16B segs), period-8 row rotation: conflict-free
// for ds_read_b128 8-lane phases (verified structure from prior session).
__device__ __forceinline__ int swz8(int row, int q) { return row * 8 + ((q + row) & 7); }
// 64B-row variant (4 x 16B segs): worst case 2-way aliasing = free (m136).
__device__ __forceinline__ int swz4(int row, int q) { return row * 4 + ((q + row) & 3); }
__device__ __forceinline__ int rot3(int i) { return i == 2 ? 0 : i + 1; }

#define GLDS16(g, l) __builtin_amdgcn_global_load_lds( \
    (__attribute__((address_space(1))) void*)(g), \
    (__attribute__((address_space(3))) void*)(l), 16, 0, 0)

// ---------------------------------------------------------------------------
// fused prepass: blocks [0,TOKENS) quantize x per-token to i8;
// blocks [TOKENS, TOKENS+2048) grid-stride convert weights
// ---------------------------------------------------------------------------
__global__ __launch_bounds__(256)
void prepass(const float* __restrict__ x,
             const float4* __restrict__ gw, const float4* __restrict__ uw,
             const float4* __restrict__ dw,
             int8_t* __restrict__ xq, float* __restrict__ xs,
             int* __restrict__ go, int* __restrict__ uo,
             f16x4* __restrict__ dno) {
    const int tid = threadIdx.x;
    if (blockIdx.x < TOKENS) {
        const int t = blockIdx.x;
        const float4* row = (const float4*)(x + (size_t)t * HIDDEN);
        float4 v0 = row[tid * 2];
        float4 v1 = row[tid * 2 + 1];
        float m = fmaxf(fmaxf(fabsf(v0.x), fabsf(v0.y)), fmaxf(fabsf(v0.z), fabsf(v0.w)));
        m = fmaxf(m, fmaxf(fmaxf(fabsf(v1.x), fabsf(v1.y)), fmaxf(fabsf(v1.z), fabsf(v1.w))));
        #pragma unroll
        for (int off = 32; off; off >>= 1)
            m = fmaxf(m, __shfl_xor(m, off, 64));
        __shared__ float wmax[4];
        if ((tid & 63) == 0) wmax[tid >> 6] = m;
        __syncthreads();
        m = fmaxf(fmaxf(wmax[0], wmax[1]), fmaxf(wmax[2], wmax[3]));
        m = fmaxf(m, 1e-20f);
        if (tid == 0) xs[t] = m * (1.0f / 127.0f);
        const float inv = 127.0f / m;
        float vals[8] = {v0.x, v0.y, v0.z, v0.w, v1.x, v1.y, v1.z, v1.w};
        int b[8];
        #pragma unroll
        for (int i = 0; i < 8; ++i) b[i] = (int)rintf(vals[i] * inv);
        int lo = (b[0] & 255) | ((b[1] & 255) << 8) | ((b[2] & 255) << 16) | (b[3] << 24);
        int hi = (b[4] & 255) | ((b[5] & 255) << 8) | ((b[6] & 255) << 16) | (b[7] << 24);
        ((int2*)(xq + (size_t)t * HIDDEN))[tid] = make_int2(lo, hi);
        return;
    }
    const int NW4 = INTER * HIDDEN / 4;
    int i = (blockIdx.x - TOKENS) * blockDim.x + tid;
    const int stride = 2048 * blockDim.x;
    for (; i < 3 * NW4; i += stride) {
        if (i < 2 * NW4) {
            const bool is_g = i < NW4;
            const int j = is_g ? i : i - NW4;
            float4 f = is_g ? gw[j] : uw[j];
            int p = ((int)(signed char)(int)f.x & 255)
                  | (((int)(signed char)(int)f.y & 255) << 8)
                  | (((int)(signed char)(int)f.z & 255) << 16)
                  | (((int)(signed char)(int)f.w) << 24);
            if (is_g) go[j] = p; else uo[j] = p;
        } else {
            const int j = i - 2 * NW4;
            float4 f = dw[j];
            f16x4 o;
            o.x = (_Float16)f.x; o.y = (_Float16)f.y;
            o.z = (_Float16)f.z; o.w = (_Float16)f.w;
            dno[j] = o;
        }
    }
}

// ---------------------------------------------------------------------------
// GEMM1 fused (i8): H = silu(G*xs*gs) * (U*xs*us)  (fp16 out)
// 128x128 tile, BK=64, ring-3 LDS (72KB, 2 blk/CU), counted vmcnt(6) pipeline
// (prefetch distance 2 tiles, never drained in steady state), raw s_barrier,
// setprio(1) around MFMA clusters. Two MFMA phases per K-tile (jn 0-1 / 2-3).
// ---------------------------------------------------------------------------
__global__ __launch_bounds__(256, 2)
void gemm_gateup(const int8_t* __restrict__ Xq,
                 const int8_t* __restrict__ Wg,
                 const int8_t* __restrict__ Wu,
                 const float* __restrict__ xs,
                 const float* __restrict__ gs,
                 const float* __restrict__ us,
                 _Float16* __restrict__ Hm) {
    __shared__ int8_t As [3][128 * BK];
    __shared__ int8_t Bgs[3][128 * BK];
    __shared__ int8_t Bus[3][128 * BK];

    const int pid   = blockIdx.x;          // 0..1407
    const int local = pid % (16 * 44);
    const int bm    = ((pid / (16 * 44)) * 16 + (local & 15)) * 128;
    const int bn    = (local >> 4) * 128;

    const int tid  = threadIdx.x;
    const int lane = tid & 63;
    const int wave = tid >> 6;
    const int wm   = (wave >> 1) * 64;
    const int wn   = (wave & 1) * 64;
    const int l15  = lane & 15;
    const int lq   = lane >> 4;

    // staging: 512 16B-slots per matrix per tile, 2 rounds of 256 threads.
    // slot f -> row f>>2, permuted global segment ((f&3) - row) & 3.
    int rowS[2], segS[2];
    #pragma unroll
    for (int j = 0; j < 2; ++j) {
        const int f = tid + 256 * j;
        rowS[j] = f >> 2;
        segS[j] = (((f & 3) - (f >> 2)) & 3) * 16;
    }

    const int8_t* gA = Xq + (size_t)bm * HIDDEN;
    const int8_t* gG = Wg + (size_t)bn * HIDDEN;
    const int8_t* gU = Wu + (size_t)bn * HIDDEN;

    i32x4 accg[4][4] = {};
    i32x4 accu[4][4] = {};

    // 3 gload_lds per call; 6 per tile per thread
    #define STG_GU(b, t, j) do { \
        const int f_ = tid + 256 * (j); \
        const size_t off_ = (size_t)rowS[j] * HIDDEN + (size_t)(t) * BK + segS[j]; \
        GLDS16(gA + off_, &As [b][f_ * 16]); \
        GLDS16(gG + off_, &Bgs[b][f_ * 16]); \
        GLDS16(gU + off_, &Bus[b][f_ * 16]); \
    } while (0)

    // prologue: tiles 0,1 in flight (12 loads); wait oldest 6 (tile 0)
    STG_GU(0, 0, 0); STG_GU(0, 0, 1);
    STG_GU(1, 1, 0); STG_GU(1, 1, 1);
    asm volatile("s_waitcnt vmcnt(6)" ::: "memory");
    __builtin_amdgcn_s_barrier();
    __builtin_amdgcn_sched_barrier(0);

    int cur = 0, stg = 2;
    for (int t = 0; t < NT_GU; ++t) {
        const int8_t* A_ = As [cur];
        const int8_t* G_ = Bgs[cur];
        const int8_t* U_ = Bus[cur];

        // ---- phase A: jn 0,1 ----
        if (t + 2 < NT_GU) STG_GU(stg, t + 2, 0);
        i32x4 a[4], b0[2], b1[2];
        #pragma unroll
        for (int im = 0; im < 4; ++im)
            a[im] = *(const i32x4*)&A_[swz4(wm + im * 16 + l15, lq) * 16];
        #pragma unroll
        for (int jn = 0; jn < 2; ++jn) {
            b0[jn] = *(const i32x4*)&G_[swz4(wn + jn * 16 + l15, lq) * 16];
            b1[jn] = *(const i32x4*)&U_[swz4(wn + jn * 16 + l15, lq) * 16];
        }
        __builtin_amdgcn_s_barrier();
        asm volatile("s_waitcnt lgkmcnt(0)");
        __builtin_amdgcn_s_setprio(1);
        #pragma unroll
        for (int jn = 0; jn < 2; ++jn)
            #pragma unroll
            for (int im = 0; im < 4; ++im) {
                accg[im][jn] = __builtin_amdgcn_mfma_i32_16x16x64_i8(a[im], b0[jn], accg[im][jn], 0, 0, 0);
                accu[im][jn] = __builtin_amdgcn_mfma_i32_16x16x64_i8(a[im], b1[jn], accu[im][jn], 0, 0, 0);
            }
        __builtin_amdgcn_s_setprio(0);
        __builtin_amdgcn_s_barrier();

        // ---- phase B: jn 2,3 (a[] reused) ----
        if (t + 2 < NT_GU) STG_GU(stg, t + 2, 1);
        #pragma unroll
        for (int jn = 0; jn < 2; ++jn) {
            b0[jn] = *(const i32x4*)&G_[swz4(wn + (jn + 2) * 16 + l15, lq) * 16];
            b1[jn] = *(const i32x4*)&U_[swz4(wn + (jn + 2) * 16 + l15, lq) * 16];
        }
        __builtin_amdgcn_s_barrier();
        asm volatile("s_waitcnt lgkmcnt(0)");
        __builtin_amdgcn_s_setprio(1);
        #pragma unroll
        for (int jn = 0; jn < 2; ++jn)
            #pragma unroll
            for (int im = 0; im < 4; ++im) {
                accg[im][jn + 2] = __builtin_amdgcn_mfma_i32_16x16x64_i8(a[im], b0[jn], accg[im][jn + 2], 0, 0, 0);
                accu[im][jn + 2] = __builtin_amdgcn_mfma_i32_16x16x64_i8(a[im], b1[jn], accu[im][jn + 2], 0, 0, 0);
            }
        __builtin_amdgcn_s_setprio(0);

        // publish tile t+1: counted wait, never 0 until the tail
        if (t < NT_GU - 2)       { asm volatile("s_waitcnt vmcnt(6)" ::: "memory"); }
        else if (t == NT_GU - 2) { asm volatile("s_waitcnt vmcnt(0)" ::: "memory"); }
        __builtin_amdgcn_s_barrier();
        __builtin_amdgcn_sched_barrier(0);

        cur = rot3(cur); stg = rot3(stg);
    }
    #undef STG_GU

    #pragma unroll
    for (int jn = 0; jn < 4; ++jn) {
        const int col = bn + wn + jn * 16 + l15;
        const float sg = gs[col];
        const float su = us[col];
        #pragma unroll
        for (int im = 0; im < 4; ++im) {
            const int rbase = bm + wm + im * 16 + lq * 4;
            #pragma unroll
            for (int r = 0; r < 4; ++r) {
                const int row = rbase + r;
                const float st = xs[row];
                float g = (float)accg[im][jn][r] * st * sg;
                float u = (float)accu[im][jn][r] * st * su;
                float h = (g / (1.0f + __expf(-g))) * u;
                Hm[(size_t)row * INTER + col] = (_Float16)h;
            }
        }
    }
}

// ---------------------------------------------------------------------------
// GEMM2 (fp16): out = (H @ Wd^T) * down_s  (fp32 out)
// 256x128 tile, 512 thr (8 waves, 4Mx2N, 64x64 each), BK=64, ring-3 LDS
// (144KB, 1 blk/CU), counted vmcnt(6) pipeline. Grid = exactly 256 blocks
// (1 per CU, no tail), XCD-chunked so each XCD's 2 Wd panels are L2-resident.
// ---------------------------------------------------------------------------
__global__ __launch_bounds__(512, 2)
void gemm_down(const _Float16* __restrict__ Hm,
               const _Float16* __restrict__ Wd,
               const float* __restrict__ dsc,
               float* __restrict__ out) {
    __shared__ _Float16 As[3][256 * BK];   // 3 x 32KB
    __shared__ _Float16 Bs[3][128 * BK];   // 3 x 16KB

    const int pid = blockIdx.x;            // 0..255
    const int p2  = (pid & 7) * 32 + (pid >> 3);   // XCD-chunked (256%8==0)
    const int bm  = (p2 & 15) * 256;
    const int bn  = (p2 >> 4) * 128;

    const int tid  = threadIdx.x;
    const int lane = tid & 63;
    const int wave = tid >> 6;             // 0..7
    const int wm   = (wave >> 1) * 64;     // 4 M-waves
    const int wn   = (wave & 1) * 64;      // 2 N-waves
    const int l15  = lane & 15;
    const int lq   = lane >> 4;

    // staging: 128B rows, 8 segs; A = 4 rounds of 512 thr, B = 2 rounds
    int rS[4], sS[4];
    #pragma unroll
    for (int j = 0; j < 4; ++j) {
        const int f = tid + 512 * j;
        rS[j] = f >> 3;
        sS[j] = (((f & 7) - (f >> 3)) & 7) * 8;   // f16 elements
    }

    const _Float16* gA = Hm + (size_t)bm * INTER;
    const _Float16* gB = Wd + (size_t)bn * INTER;

    f32x4 acc[4][4] = {};

    #define STG_DA(b, t, j) do { \
        const int f_ = tid + 512 * (j); \
        GLDS16(gA + (size_t)rS[j] * INTER + (size_t)(t) * BK + sS[j], &As[b][f_ * 8]); \
    } while (0)
    #define STG_DB(b, t, j) do { \
        const int f_ = tid + 512 * (j); \
        GLDS16(gB + (size_t)rS[j] * INTER + (size_t)(t) * BK + sS[j], &Bs[b][f_ * 8]); \
    } while (0)

    // prologue: tiles 0,1 (12 loads); wait oldest 6 (tile 0)
    STG_DA(0, 0, 0); STG_DA(0, 0, 1); STG_DA(0, 0, 2); STG_DA(0, 0, 3);
    STG_DB(0, 0, 0); STG_DB(0, 0, 1);
    STG_DA(1, 1, 0); STG_DA(1, 1, 1); STG_DA(1, 1, 2); STG_DA(1, 1, 3);
    STG_DB(1, 1, 0); STG_DB(1, 1, 1);
    asm volatile("s_waitcnt vmcnt(6)" ::: "memory");
    __builtin_amdgcn_s_barrier();
    __builtin_amdgcn_sched_barrier(0);

    int cur = 0, stg = 2;
    for (int t = 0; t < NT_DN; ++t) {
        const _Float16* A_ = As[cur];
        const _Float16* B_ = Bs[cur];

        // ---- phase 0: k-step 0 ----
        if (t + 2 < NT_DN) { STG_DA(stg, t + 2, 0); STG_DA(stg, t + 2, 1); STG_DB(stg, t + 2, 0); }
        {
            f16x8 a[4], b[4];
            #pragma unroll
            for (int im = 0; im < 4; ++im)
                a[im] = *(const f16x8*)&A_[swz8(wm + im * 16 + l15, lq) * 8];
            #pragma unroll
            for (int jn = 0; jn < 4; ++jn)
                b[jn] = *(const f16x8*)&B_[swz8(wn + jn * 16 + l15, lq) * 8];
            __builtin_amdgcn_s_barrier();
            asm volatile("s_waitcnt lgkmcnt(0)");
            __builtin_amdgcn_s_setprio(1);
            #pragma unroll
            for (int jn = 0; jn < 4; ++jn)
                #pragma unroll
                for (int im = 0; im < 4; ++im)
                    acc[im][jn] = __builtin_amdgcn_mfma_f32_16x16x32_f16(a[im], b[jn], acc[im][jn], 0, 0, 0);
            __builtin_amdgcn_s_setprio(0);
            __builtin_amdgcn_s_barrier();
        }

        // ---- phase 1: k-step 1 ----
        if (t + 2 < NT_DN) { STG_DA(stg, t + 2, 2); STG_DA(stg, t + 2, 3); STG_DB(stg, t + 2, 1); }
        {
            f16x8 a[4], b[4];
            #pragma unroll
            for (int im = 0; im < 4; ++im)
                a[im] = *(const f16x8*)&A_[swz8(wm + im * 16 + l15, 4 + lq) * 8];
            #pragma unroll
            for (int jn = 0; jn < 4; ++jn)
                b[jn] = *(const f16x8*)&B_[swz8(wn + jn * 16 + l15, 4 + lq) * 8];
            __builtin_amdgcn_s_barrier();
            asm volatile("s_waitcnt lgkmcnt(0)");
            __builtin_amdgcn_s_setprio(1);
            #pragma unroll
            for (int jn = 0; jn < 4; ++jn)
                #pragma unroll
                for (int im = 0; im < 4; ++im)
                    acc[im][jn] = __builtin_amdgcn_mfma_f32_16x16x32_f16(a[im], b[jn], acc[im][jn], 0, 0, 0);
            __builtin_amdgcn_s_setprio(0);
        }

        if (t < NT_DN - 2)       { asm volatile("s_waitcnt vmcnt(6)" ::: "memory"); }
        else if (t == NT_DN - 2) { asm volatile("s_waitcnt vmcnt(0)" ::: "memory"); }
        __builtin_amdgcn_s_barrier();
        __builtin_amdgcn_sched_barrier(0);

        cur = rot3(cur); stg = rot3(stg);
    }
    #undef STG_DA
    #undef STG_DB

    #pragma unroll
    for (int jn = 0; jn < 4; ++jn) {
        const int col = bn + wn + jn * 16 + l15;
        const float sd = dsc[col];
        #pragma unroll
        for (int im = 0; im < 4; ++im) {
            const int rbase = bm + wm + im * 16 + lq * 4;
            #pragma unroll
            for (int r = 0; r < 4; ++r)
                out[(size_t)(rbase + r) * HIDDEN + col] = acc[im][jn][r] * sd;
        }
    }
}

// ---------------------------------------------------------------------------
// launch
// ---------------------------------------------------------------------------
extern "C" void kernel_launch(void* const* d_in, const int* in_sizes, int n_in,
                              void* d_out, int out_size, void* d_ws, size_t ws_size,
                              hipStream_t stream) {
    const float* x   = (const float*)d_in[0];
    const float* gw  = (const float*)d_in[1];
    const float* uw  = (const float*)d_in[2];
    const float* dw  = (const float*)d_in[3];
    const float* gsc = (const float*)d_in[4];
    const float* usc = (const float*)d_in[5];
    const float* dsc = (const float*)d_in[6];
    float* out = (float*)d_out;

    // workspace layout:
    //   Xq  i8  @          0 :  8,388,608
    //   Wg8 i8  @  8,388,608 : 11,534,336
    //   Wu8 i8  @ 19,922,944 : 11,534,336
    //   Wdh f16 @ 31,457,280 : 23,068,672
    //   Hm  f16 @ 54,525,952 : 46,137,344
    //   xs  f32 @100,663,296 :     16,384
    char* ws = (char*)d_ws;
    int8_t*   Xq  = (int8_t*)(ws);
    int8_t*   Wg8 = (int8_t*)(ws + 8388608ull);
    int8_t*   Wu8 = (int8_t*)(ws + 19922944ull);
    _Float16* Wdh = (_Float16*)(ws + 31457280ull);
    _Float16* Hm  = (_Float16*)(ws + 54525952ull);
    float*    xs  = (float*)(ws + 100663296ull);

    prepass<<<TOKENS + 2048, 256, 0, stream>>>(
        x, (const float4*)gw, (const float4*)uw, (const float4*)dw,
        Xq, xs, (int*)Wg8, (int*)Wu8, (f16x4*)Wdh);

    gemm_gateup<<<(INTER / 128) * (TOKENS / 128), 256, 0, stream>>>(
        Xq, Wg8, Wu8, xs, gsc, usc, Hm);
    gemm_down<<<(HIDDEN / 128) * (TOKENS / 256), 512, 0, stream>>>(
        Hm, Wdh, dsc, out);
}